// Round 7
// baseline (755.160 us; speedup 1.0000x reference)
//
#include <hip/hip_runtime.h>

// ContrastiveGNN: 3x GCNConv(relu) + 2-layer projector MLP.
// N=100000 nodes, E=1600000 edges, IN_D=256, HID=OUT_D=64.
// Round 7: algebraic refactor — GEMM epilogue scales rows by deg_rs, so
// gather needs no per-edge weight: out = relu(drs[d]*(h'[d]+sum h'[s]) + b).
// csr_fill now writes only csr_src (one scattered line per edge, not two).

#define BLK 256
#define SCAN_CHUNK 1024

// ---------------- degree (int histogram) ----------------
__global__ void count_deg_kernel(const int* __restrict__ dst, int* __restrict__ deg_cnt, int E) {
    int e = blockIdx.x * BLK + threadIdx.x;
    if (e < E) atomicAdd(&deg_cnt[dst[e]], 1);
}

__global__ void deg_finalize_kernel(const int* __restrict__ deg_cnt,
                                    float* __restrict__ deg_rs, int N) {
    int i = blockIdx.x * BLK + threadIdx.x;
    if (i < N) {
        float d = (float)deg_cnt[i] + 1.0f;   // +1 self loop
        deg_rs[i] = rsqrtf(d);
    }
}

// ---------------- exclusive scan of deg_cnt -> rowptr (3 kernels) ----------------
__global__ void scan_reduce_kernel(const int* __restrict__ cnt, int* __restrict__ bsum, int N) {
    __shared__ int red[BLK];
    int base = blockIdx.x * SCAN_CHUNK;
    int s = 0;
    for (int i = threadIdx.x; i < SCAN_CHUNK; i += BLK) {
        int g = base + i;
        s += (g < N) ? cnt[g] : 0;
    }
    red[threadIdx.x] = s;
    __syncthreads();
    for (int off = BLK / 2; off > 0; off >>= 1) {
        if (threadIdx.x < off) red[threadIdx.x] += red[threadIdx.x + off];
        __syncthreads();
    }
    if (threadIdx.x == 0) bsum[blockIdx.x] = red[0];
}

__global__ void scan_top_kernel(int* __restrict__ bsum, int NB) {
    if (blockIdx.x == 0 && threadIdx.x == 0) {
        int acc = 0;
        for (int i = 0; i < NB; ++i) { int v = bsum[i]; bsum[i] = acc; acc += v; }
    }
}

__global__ void scan_final_kernel(const int* __restrict__ cnt, const int* __restrict__ bsum,
                                  int* __restrict__ rowptr, int* __restrict__ cursor, int N, int E) {
    __shared__ int ts[BLK];
    int base = blockIdx.x * SCAN_CHUNK;
    int tb = base + threadIdx.x * 4;
    int v[4];
    int mySum = 0;
#pragma unroll
    for (int j = 0; j < 4; ++j) {
        int g = tb + j;
        v[j] = (g < N) ? cnt[g] : 0;
        mySum += v[j];
    }
    ts[threadIdx.x] = mySum;
    __syncthreads();
    for (int off = 1; off < BLK; off <<= 1) {
        int t = (threadIdx.x >= off) ? ts[threadIdx.x - off] : 0;
        __syncthreads();
        ts[threadIdx.x] += t;
        __syncthreads();
    }
    int excl = ts[threadIdx.x] - mySum + bsum[blockIdx.x];
#pragma unroll
    for (int j = 0; j < 4; ++j) {
        int g = tb + j;
        if (g < N) { rowptr[g] = excl; cursor[g] = excl; }
        excl += v[j];
    }
    if (blockIdx.x == 0 && threadIdx.x == 0) rowptr[N] = E;
}

// ---------------- CSR fill: bucket edge src by dst ----------------
__global__ void csr_fill_kernel(const int* __restrict__ src, const int* __restrict__ dst,
                                int* __restrict__ cursor, int* __restrict__ csr_src, int E) {
    int e = blockIdx.x * BLK + threadIdx.x;
    if (e < E) {
        int pos = atomicAdd(&cursor[dst[e]], 1);
        csr_src[pos] = src[e];
    }
}

// ---------------- LDS-staged GEMM: [N,K] x [K,64] -> [N,64] ----------------
// 256 threads = 128 rows x 2 col-halves. x chunk (128 x 64) staged in LDS
// with pad-65 stride. W rows via wave-uniform scalar loads.
// MODE: 0=raw, 1=bias+relu, 2=bias, 3=scale rows by scale[row] (deg_rs)
template <int K, int MODE>
__global__ __launch_bounds__(256) void gemm_lds_kernel(const float* __restrict__ x,
                                                       const float* __restrict__ W,
                                                       const float* __restrict__ b,
                                                       const float* __restrict__ scale,
                                                       float* __restrict__ out, int N) {
    constexpr int KC = 64;   // k-chunk
    __shared__ float xs[128 * 65];   // 33.3 KB
    const int tid  = threadIdx.x;
    const int row  = tid & 127;
    const int half = __builtin_amdgcn_readfirstlane(threadIdx.x >> 7);  // 0/1, wave-uniform
    const int row0 = blockIdx.x * 128;

    float acc[32];
#pragma unroll
    for (int c = 0; c < 32; ++c) acc[c] = 0.f;

    for (int kc = 0; kc < K; kc += KC) {
        __syncthreads();   // protect xs from previous chunk's readers
#pragma unroll
        for (int i = 0; i < 8; ++i) {
            int q  = i * 256 + tid;          // float4 index in [0, 2048)
            int r  = q >> 4;                 // 16 float4 per row
            int j4 = q & 15;
            int gr = row0 + r; if (gr >= N) gr = N - 1;
            const float4 v = *(const float4*)(x + (size_t)gr * K + kc + j4 * 4);
            float* d = &xs[r * 65 + j4 * 4];
            d[0] = v.x; d[1] = v.y; d[2] = v.z; d[3] = v.w;
        }
        __syncthreads();

        const float* Wbase = W + (size_t)kc * 64 + half * 32;
#pragma unroll 2
        for (int k = 0; k < KC; ++k) {
            float xv = xs[row * 65 + k];
            const float* Wr = Wbase + (size_t)k * 64;   // uniform -> s_load
#pragma unroll
            for (int c = 0; c < 32; ++c) acc[c] = fmaf(xv, Wr[c], acc[c]);
        }
    }

    int gr = row0 + row;
    if (gr < N) {
        float* o = out + (size_t)gr * 64 + half * 32;
        float sc = (MODE == 3) ? scale[gr] : 1.f;
#pragma unroll
        for (int c = 0; c < 32; ++c) {
            float v = acc[c];
            if (MODE == 3)      v *= sc;
            else if (MODE != 0) v += b[half * 32 + c];
            if (MODE == 1)      v = fmaxf(v, 0.f);
            o[c] = v;
        }
    }
}

// ---------------- gather-aggregate + fused epilogue ----------------
// h is pre-scaled by deg_rs (GEMM MODE 3). One wave per node, lane = feature.
// out = relu(drs[d] * (h[d] + sum h[src]) + b)
__global__ void gcn_gather_kernel(const float* __restrict__ h,
                                  const int* __restrict__ rowptr,
                                  const int* __restrict__ csr_src,
                                  const float* __restrict__ deg_rs,
                                  const float* __restrict__ b,
                                  float* __restrict__ out, int N) {
    int node = blockIdx.x * 4 + (threadIdx.x >> 6);
    int f    = threadIdx.x & 63;
    if (node >= N) return;
    int beg = rowptr[node], end = rowptr[node + 1];
    float acc = h[(size_t)node * 64 + f];   // self loop (h pre-scaled)
    int i = beg;
    for (; i + 4 <= end; i += 4) {
        int s0 = csr_src[i],     s1 = csr_src[i + 1];
        int s2 = csr_src[i + 2], s3 = csr_src[i + 3];
        acc += h[(size_t)s0 * 64 + f];
        acc += h[(size_t)s1 * 64 + f];
        acc += h[(size_t)s2 * 64 + f];
        acc += h[(size_t)s3 * 64 + f];
    }
    for (; i < end; ++i) acc += h[(size_t)csr_src[i] * 64 + f];
    out[(size_t)node * 64 + f] = fmaxf(fmaf(acc, deg_rs[node], b[f]), 0.f);
}

extern "C" void kernel_launch(void* const* d_in, const int* in_sizes, int n_in,
                              void* d_out, int out_size, void* d_ws, size_t ws_size,
                              hipStream_t stream) {
    const float* x   = (const float*)d_in[0];
    const float* W1  = (const float*)d_in[1];
    const float* b1  = (const float*)d_in[2];
    const float* W2  = (const float*)d_in[3];
    const float* b2  = (const float*)d_in[4];
    const float* W3  = (const float*)d_in[5];
    const float* b3  = (const float*)d_in[6];
    const float* Pw1 = (const float*)d_in[7];
    const float* Pb1 = (const float*)d_in[8];
    const float* Pw2 = (const float*)d_in[9];
    const float* Pb2 = (const float*)d_in[10];
    const int*   ei  = (const int*)d_in[11];

    const int N = in_sizes[0] / 256;
    const int E = in_sizes[11] / 2;
    const int* src = ei;
    const int* dst = ei + E;

    // workspace layout (all 4-byte types)
    char* p = (char*)d_ws;
    float* deg_rs  = (float*)p;                 p += (size_t)N * 4;
    float* X       = (float*)p;                 p += (size_t)N * 64 * 4;
    float* H       = (float*)p;                 p += (size_t)N * 64 * 4;
    int*   deg_cnt = (int*)p;                   p += (size_t)N * 4;
    int*   rowptr  = (int*)p;                   p += ((size_t)N + 1) * 4;
    int*   cursor  = (int*)p;                   p += (size_t)N * 4;
    int*   bsum    = (int*)p;                   p += 128 * 4;
    int*   csr_src = (int*)p;                   p += (size_t)E * 4;

    const int gNode = (N + BLK - 1) / BLK;
    const int gRows = (N + 3) / 4;        // gather: 4 nodes/block
    const int gGemm = (N + 127) / 128;    // gemm: 128 rows/block
    const int gEdge = (E + BLK - 1) / BLK;
    const int NB    = (N + SCAN_CHUNK - 1) / SCAN_CHUNK;

    // ---- degree + CSR build ----
    hipMemsetAsync(deg_cnt, 0, (size_t)N * sizeof(int), stream);
    count_deg_kernel<<<gEdge, BLK, 0, stream>>>(dst, deg_cnt, E);
    deg_finalize_kernel<<<gNode, BLK, 0, stream>>>(deg_cnt, deg_rs, N);
    scan_reduce_kernel<<<NB, BLK, 0, stream>>>(deg_cnt, bsum, N);
    scan_top_kernel<<<1, BLK, 0, stream>>>(bsum, NB);
    scan_final_kernel<<<NB, BLK, 0, stream>>>(deg_cnt, bsum, rowptr, cursor, N, E);
    csr_fill_kernel<<<gEdge, BLK, 0, stream>>>(src, dst, cursor, csr_src, E);

    // ---- layer 1 ----
    gemm_lds_kernel<256, 3><<<gGemm, BLK, 0, stream>>>(x, W1, nullptr, deg_rs, H, N);
    gcn_gather_kernel<<<gRows, BLK, 0, stream>>>(H, rowptr, csr_src, deg_rs, b1, X, N);

    // ---- layer 2 ----
    gemm_lds_kernel<64, 3><<<gGemm, BLK, 0, stream>>>(X, W2, nullptr, deg_rs, H, N);
    gcn_gather_kernel<<<gRows, BLK, 0, stream>>>(H, rowptr, csr_src, deg_rs, b2, X, N);

    // ---- layer 3 ----
    gemm_lds_kernel<64, 3><<<gGemm, BLK, 0, stream>>>(X, W3, nullptr, deg_rs, H, N);
    gcn_gather_kernel<<<gRows, BLK, 0, stream>>>(H, rowptr, csr_src, deg_rs, b3, X, N);

    // ---- projector ----
    gemm_lds_kernel<64, 1><<<gGemm, BLK, 0, stream>>>(X, Pw1, Pb1, nullptr, H, N);
    gemm_lds_kernel<64, 2><<<gGemm, BLK, 0, stream>>>(H, Pw2, Pb2, nullptr, (float*)d_out, N);
}